// Round 1
// 235.586 us; speedup vs baseline: 1.1223x; 1.1223x over previous
//
#include <hip/hip_runtime.h>
#include <hip/hip_bf16.h>

typedef __attribute__((ext_vector_type(8))) short bf16x8;  // 8 bf16 = 4 VGPRs
typedef __attribute__((ext_vector_type(4))) float f32x4;   // MFMA C/D
typedef __attribute__((ext_vector_type(4))) int   i32x4;

#define BIGC 10000.0f
#define TPW 4          // macro-iterations (64 points per wave each)
#define WAVES 4

__device__ __forceinline__ float fast_exp2(float x) { return __builtin_amdgcn_exp2f(x); }
__device__ __forceinline__ float fast_log2(float x) { return __builtin_amdgcn_logf(x); }
__device__ __forceinline__ float fast_rcp(float x)  { return __builtin_amdgcn_rcpf(x); }

__device__ __forceinline__ float fast_tanh(float x) {
    const float ax = fabsf(x);
    const float e  = fast_exp2(ax * 2.8853900817779268f);   // e^(2|x|)
    const float r  = 1.0f - 2.0f * fast_rcp(e + 1.0f);
    return copysignf(r, x);
}
__device__ __forceinline__ float fast_softplus(float v) {
    const float e = fast_exp2(fabsf(v) * -1.4426950408889634f);  // exp(-|v|)
    const float l = fast_log2(1.0f + e) * 0.6931471805599453f;   // ln(1+e)
    return fmaxf(v, 0.0f) + l;
}
// Pack two f32 -> two bf16 (RNE) in ONE instruction (was 2 v_add + v_perm).
__device__ __forceinline__ unsigned pack2bf(float hi, float lo) {
    unsigned r;
    asm("v_cvt_pk_bf16_f32 %0, %1, %2" : "=v"(r) : "v"(lo), "v"(hi));
    return r;
}

// MFMA 16x16x32 layouts (verified in earlier rounds):
//   A: lane holds A[m=lane&15][k=(lane>>4)*8+j]
//   B: lane holds B[k=(lane>>4)*8+j][n=lane&15]
//   C/D: lane holds D[row=(lane>>4)*4+reg][col=lane&15]
//
// GEMM1 TRANSPOSED: h^T(64x16) = W1'^T(64x19) @ z^T(19x16), 4 M-tiles (a).
//   z k-slots: k<16 -> t_feat[k]; k=16 -> tanh(x0); k=17 -> tanh(x1);
//              k=18 -> 1.0 (bias row, A value = b1); k>18 -> 0.
// GEMM2 NORMAL: d(16x10) = h(16x64) @ W2sig(64x10); sigma K-permutation folded
//   into W2 row order so A-frag comes from SAME-LANE relu(acc) repack (no LDS).
//
// This version: all global loads hoisted to iteration top (registers), 32-bit
// addressing (wave-uniform clamped base), tanh computed once per lane on the
// interp x-values and broadcast to the z-fragment via ds_bpermute.
__global__ void __launch_bounds__(256, 4) coupling_mfma4(
    const float* __restrict__ x, const float* __restrict__ t_feat,
    const float* __restrict__ mask, const float* __restrict__ W1,
    const float* __restrict__ b1, const float* __restrict__ W2,
    const float* __restrict__ b2, float* __restrict__ out, int n)
{
    // Only d needs LDS (feat index must move across lanes for interp).
    // Wave-private; stride 11 dwords (gcd(11,32)=1 -> conflict-free).
    __shared__ float lds_d[WAVES][64][11];

    const int wave = threadIdx.x >> 6;
    const int lane = threadIdx.x & 63;
    const int m    = lane & 15;
    const int q    = lane >> 4;
    const int m4   = m << 2;

    // ---- constant fragments (built once, resident in VGPRs) ----
    bf16x8 w1f[4];   // GEMM1 A-frags: lane (q,m) elem j = W1row(sigma_z(8q+j))[16a+m]
#pragma unroll
    for (int a = 0; a < 4; ++a) {
        float wv[8];
#pragma unroll
        for (int j = 0; j < 8; ++j) {
            const int k = q * 8 + j;
            const int col = 16 * a + m;
            float v = 0.0f;
            if (k < 16)       v = W1[(k + 2) * 64 + col];
            else if (k == 16) v = W1[0 * 64 + col];
            else if (k == 17) v = W1[1 * 64 + col];
            else if (k == 18) v = b1[col];          // bias folded in
            wv[j] = v;
        }
        i32x4 f = { (int)pack2bf(wv[1], wv[0]), (int)pack2bf(wv[3], wv[2]),
                    (int)pack2bf(wv[5], wv[4]), (int)pack2bf(wv[7], wv[6]) };
        w1f[a] = __builtin_bit_cast(bf16x8, f);
    }
    bf16x8 w2f[2];   // GEMM2 B-frags with sigma row-permutation
#pragma unroll
    for (int fi = 0; fi < 2; ++fi) {
        float wv[8];
#pragma unroll
        for (int j = 0; j < 8; ++j) {
            const int hid = 32 * fi + 16 * (j >> 2) + 4 * q + (j & 3);
            wv[j] = (m < 10) ? W2[hid * 10 + m] : 0.0f;
        }
        i32x4 f = { (int)pack2bf(wv[1], wv[0]), (int)pack2bf(wv[3], wv[2]),
                    (int)pack2bf(wv[5], wv[4]), (int)pack2bf(wv[7], wv[6]) };
        w2f[fi] = __builtin_bit_cast(bf16x8, f);
    }
    const float bias2 = (m < 10) ? b2[m] : 0.0f;
    const float m0 = mask[0], m1 = mask[1];

    for (int it = 0; it < TPW; ++it) {
        // Wave-uniform base, clamped so the full 64-point tile is in-bounds
        // (duplicate recompute at the tail writes identical values — benign).
        int pb = (blockIdx.x * TPW + it) * (WAVES * 64) + wave * 64;
        pb = min(pb, n - 64);
        pb = max(pb, 0);

        // ==== phase A: issue ALL global loads for this iteration ====
        // xi first (needed earliest, for pk), then the 8 t_feat dwordx4 —
        // vmcnt counting lets sub-tiles 1-3 stay in flight under sub-tile 0.
        const int pl  = pb + lane;
        const int plc = min(pl, n - 1);          // load-clamp (n<64 safety)
        const float* xp = x + plc * 3;
        const float xi0 = xp[0], xi1 = xp[1], xi2 = xp[2];

        float4 ta[4], tb[4];
        if (q < 2) {
#pragma unroll
            for (int s = 0; s < 4; ++s) {
                const int ps = min(pb + 16 * s + m, n - 1);
                const float4* tr = (const float4*)(t_feat + ps * 16 + q * 8);
                ta[s] = tr[0];
                tb[s] = tr[1];
            }
        }

        // tanh once per lane on its own point; z-frag pulls it via bpermute.
        const unsigned pk = pack2bf(fast_tanh(xi1), fast_tanh(xi0));

        // ==== phase B: 4 sub-tiles of 16 points ====
#pragma unroll
        for (int s = 0; s < 4; ++s) {
            // lane (q=2,m) needs point pb+16s+m -> lives in lane 16s+m
            const int tp = __builtin_amdgcn_ds_bpermute(s * 64 + m4, (int)pk);

            i32x4 zw = { 0, 0, 0, 0 };
            if (q < 2) {
                zw[0] = (int)pack2bf(ta[s].y, ta[s].x);
                zw[1] = (int)pack2bf(ta[s].w, ta[s].z);
                zw[2] = (int)pack2bf(tb[s].y, tb[s].x);
                zw[3] = (int)pack2bf(tb[s].w, tb[s].z);
            } else if (q == 2) {
                zw[0] = tp;                        // [tanh(x1)|tanh(x0)]
                zw[1] = 0x3F80;                    // k=18: bf16(1.0) bias slot
            }
            const bf16x8 zf = __builtin_bit_cast(bf16x8, zw);

            // ---- GEMM1 (transposed): 4 independent MFMAs, bias folded ----
            f32x4 acc[4];
#pragma unroll
            for (int a = 0; a < 4; ++a) {
                f32x4 c = { 0.0f, 0.0f, 0.0f, 0.0f };
                acc[a] = __builtin_amdgcn_mfma_f32_16x16x32_bf16(w1f[a], zf, c, 0, 0, 0);
            }

            // ---- relu + IN-LANE repack to GEMM2 A-frags (no LDS!) ----
            float rl[16];
#pragma unroll
            for (int a = 0; a < 4; ++a)
#pragma unroll
                for (int r = 0; r < 4; ++r)
                    rl[4 * a + r] = fmaxf(acc[a][r], 0.0f);
            i32x4 a20 = { (int)pack2bf(rl[1],  rl[0]),  (int)pack2bf(rl[3],  rl[2]),
                          (int)pack2bf(rl[5],  rl[4]),  (int)pack2bf(rl[7],  rl[6]) };
            i32x4 a21 = { (int)pack2bf(rl[9],  rl[8]),  (int)pack2bf(rl[11], rl[10]),
                          (int)pack2bf(rl[13], rl[12]), (int)pack2bf(rl[15], rl[14]) };

            // ---- GEMM2: two INDEPENDENT MFMAs, summed after ----
            f32x4 cb = { bias2, bias2, bias2, bias2 };
            f32x4 cz = { 0.0f, 0.0f, 0.0f, 0.0f };
            f32x4 cd0 = __builtin_amdgcn_mfma_f32_16x16x32_bf16(
                            __builtin_bit_cast(bf16x8, a20), w2f[0], cb, 0, 0, 0);
            f32x4 cd1 = __builtin_amdgcn_mfma_f32_16x16x32_bf16(
                            __builtin_bit_cast(bf16x8, a21), w2f[1], cz, 0, 0, 0);

            // ---- softplus + d to LDS (2-way max bank aliasing = free) ----
#pragma unroll
            for (int r = 0; r < 4; ++r) {
                const float dv = fast_softplus(cd0[r] + cd1[r]) + 0.0001f;
                if (m < 10) lds_d[wave][16 * s + 4 * q + r][m] = dv;
            }
        }

        // ==== phase C: interp + store, all 64 lanes, one point each ====
        {
            const float* dd = lds_d[wave][lane];
            const float dxl2 = dd[0], dxl1 = dd[1], dxr1 = dd[2], dxr2 = dd[3];
            const float dyl2 = dd[4], dyl1 = dd[5], dyr1 = dd[6], dyr2 = dd[7];
            const float kl = dd[8] * 2.0f, kr = dd[9] * 2.0f;

            const float xL1 = -dxl1,        yL1 = -dyl1;
            const float xL2 = -dxl1 - dxl2, yL2 = -dyl1 - dyl2;
            const float xR1 = dxr1,         yR1 = dyr1;
            const float xR2 = dxr1 + dxr2,  yR2 = dyr1 + dyr2;
            const float xR3 = xR2 + BIGC,   yR3 = fmaf(kr, BIGC, yR2);
            const float xL3 = xL2 - BIGC,   yL3 = fmaf(-kl, BIGC, yL2);

            float qx = fminf(fmaxf(xi2, xL3 * 0.99f), xR3 * 0.99f);
            float xl = xL3, xrr = xL2, yl = yL3, yr = yL2;
            if (qx >= xL2) { xl = xL2; xrr = xL1; yl = yL2; yr = yL1; }
            if (qx >= xL1) { xl = xL1; xrr = xR1; yl = yL1; yr = yR1; }
            if (qx >= xR1) { xl = xR1; xrr = xR2; yl = yR1; yr = yR2; }
            if (qx >= xR2) { xl = xR2; xrr = xR3; yl = yR2; yr = yR3; }
            const float slope = (yr - yl) * fast_rcp(xrr - xl);
            const float res = fmaf(slope, qx - xl, yl);

            if (pl < n) {
                float* op = out + pl * 3;
                op[0] = xi0 * m0;
                op[1] = xi1 * m1;
                op[2] = res;
            }
        }
    }
}

extern "C" void kernel_launch(void* const* d_in, const int* in_sizes, int n_in,
                              void* d_out, int out_size, void* d_ws, size_t ws_size,
                              hipStream_t stream) {
    const float* x      = (const float*)d_in[0];
    const float* t_feat = (const float*)d_in[1];
    const float* mask   = (const float*)d_in[2];
    const float* W1     = (const float*)d_in[3];
    const float* b1     = (const float*)d_in[4];
    const float* W2     = (const float*)d_in[5];
    const float* b2     = (const float*)d_in[6];
    float* out = (float*)d_out;

    const int n = in_sizes[0] / 3;                       // 2097152 points
    const int pts_per_block = TPW * WAVES * 64;          // 1024
    const int grid = (n + pts_per_block - 1) / pts_per_block;   // 2048
    coupling_mfma4<<<grid, 256, 0, stream>>>(x, t_feat, mask, W1, b1, W2, b2, out, n);
}

// Round 2
// 235.295 us; speedup vs baseline: 1.1237x; 1.0012x over previous
//
#include <hip/hip_runtime.h>
#include <hip/hip_bf16.h>

typedef __attribute__((ext_vector_type(8))) short bf16x8;  // 8 bf16 = 4 VGPRs
typedef __attribute__((ext_vector_type(4))) float f32x4;   // MFMA C/D
typedef __attribute__((ext_vector_type(4))) int   i32x4;

#define BIGC 10000.0f
#define TPW 4          // macro-iterations (64 points per wave each)
#define WAVES 4

__device__ __forceinline__ float fast_exp2(float x) { return __builtin_amdgcn_exp2f(x); }
__device__ __forceinline__ float fast_log2(float x) { return __builtin_amdgcn_logf(x); }
__device__ __forceinline__ float fast_rcp(float x)  { return __builtin_amdgcn_rcpf(x); }

__device__ __forceinline__ float fast_tanh(float x) {
    const float ax = fabsf(x);
    const float e  = fast_exp2(ax * 2.8853900817779268f);   // e^(2|x|)
    const float r  = 1.0f - 2.0f * fast_rcp(e + 1.0f);
    return copysignf(r, x);
}
__device__ __forceinline__ float fast_softplus(float v) {
    const float e = fast_exp2(fabsf(v) * -1.4426950408889634f);  // exp(-|v|)
    const float l = fast_log2(1.0f + e) * 0.6931471805599453f;   // ln(1+e)
    return fmaxf(v, 0.0f) + l;
}
// Pack two f32 -> two bf16 (RNE) in ONE instruction.
__device__ __forceinline__ unsigned pack2bf(float hi, float lo) {
    unsigned r;
    asm("v_cvt_pk_bf16_f32 %0, %1, %2" : "=v"(r) : "v"(lo), "v"(hi));
    return r;
}

// MFMA 16x16x32 layouts (verified in earlier rounds):
//   A: lane holds A[m=lane&15][k=(lane>>4)*8+j]
//   B: lane holds B[k=(lane>>4)*8+j][n=lane&15]
//   C/D: lane holds D[row=(lane>>4)*4+reg][col=lane&15]
//
// GEMM1 TRANSPOSED: h^T(64x16) = W1'^T(64x19) @ z^T(19x16), 4 M-tiles (a).
//   z k-slots: k<16 -> t_feat[k]; k=16 -> tanh(x0); k=17 -> tanh(x1);
//              k=18 -> 1.0 (bias row, A value = b1); k>18 -> 0.
// GEMM2 NORMAL: d(16x10) = h(16x64) @ W2sig(64x10); sigma K-permutation folded
//   into W2 row order so A-frag comes from SAME-LANE relu(acc) repack (no LDS).
//
// R2 version: SoA phase pipeline (all bpermutes/packs -> all 16 GEMM1 MFMAs ->
// all repacks -> all 8 GEMM2 MFMAs -> all softplus) so the 4 independent
// sub-tiles overlap instead of serializing; x/t_feat loads software-pipelined
// one iteration ahead (issued right after current packs free the registers).
// launch_bounds(256,3): ~150 VGPR live at GEMM1 peak, avoid spill.
__global__ void __launch_bounds__(256, 3) coupling_mfma5(
    const float* __restrict__ x, const float* __restrict__ t_feat,
    const float* __restrict__ mask, const float* __restrict__ W1,
    const float* __restrict__ b1, const float* __restrict__ W2,
    const float* __restrict__ b2, float* __restrict__ out, int n)
{
    // Only d needs LDS (feat index must move across lanes for interp).
    // Wave-private; stride 11 dwords (gcd(11,32)=1 -> 2-way max = free).
    __shared__ float lds_d[WAVES][64][11];

    const int wave = threadIdx.x >> 6;
    const int lane = threadIdx.x & 63;
    const int m    = lane & 15;
    const int q    = lane >> 4;
    const int m4   = m << 2;

    // ---- constant fragments (built once, resident in VGPRs) ----
    bf16x8 w1f[4];   // GEMM1 A-frags: lane (q,m) elem j = W1row(sigma_z(8q+j))[16a+m]
#pragma unroll
    for (int a = 0; a < 4; ++a) {
        float wv[8];
#pragma unroll
        for (int j = 0; j < 8; ++j) {
            const int k = q * 8 + j;
            const int col = 16 * a + m;
            float v = 0.0f;
            if (k < 16)       v = W1[(k + 2) * 64 + col];
            else if (k == 16) v = W1[0 * 64 + col];
            else if (k == 17) v = W1[1 * 64 + col];
            else if (k == 18) v = b1[col];          // bias folded in
            wv[j] = v;
        }
        i32x4 f = { (int)pack2bf(wv[1], wv[0]), (int)pack2bf(wv[3], wv[2]),
                    (int)pack2bf(wv[5], wv[4]), (int)pack2bf(wv[7], wv[6]) };
        w1f[a] = __builtin_bit_cast(bf16x8, f);
    }
    bf16x8 w2f[2];   // GEMM2 B-frags with sigma row-permutation
#pragma unroll
    for (int fi = 0; fi < 2; ++fi) {
        float wv[8];
#pragma unroll
        for (int j = 0; j < 8; ++j) {
            const int hid = 32 * fi + 16 * (j >> 2) + 4 * q + (j & 3);
            wv[j] = (m < 10) ? W2[hid * 10 + m] : 0.0f;
        }
        i32x4 f = { (int)pack2bf(wv[1], wv[0]), (int)pack2bf(wv[3], wv[2]),
                    (int)pack2bf(wv[5], wv[4]), (int)pack2bf(wv[7], wv[6]) };
        w2f[fi] = __builtin_bit_cast(bf16x8, f);
    }
    const float bias2 = (m < 10) ? b2[m] : 0.0f;
    const float m0 = mask[0], m1 = mask[1];

    // wave's base point for it=0; per-iteration stride is WAVES*64 = 256
    const int pbase = blockIdx.x * (TPW * WAVES * 64) + wave * 64;

    // ==== prologue: loads for it=0 ====
    // (pb clamped wave-uniformly so the whole 64-pt tile is in-bounds; tail
    //  points get recomputed by multiple waves with identical values — benign.
    //  Assumes n >= 64, true for this problem.)
    float4 tA[4], tB[4];
    float xi0, xi1, xi2;
    {
        const int pb = max(min(pbase, n - 64), 0);
        const float* xp = x + (pb + lane) * 3;
        xi0 = xp[0]; xi1 = xp[1]; xi2 = xp[2];
        if (q < 2) {
#pragma unroll
            for (int s = 0; s < 4; ++s) {
                const float4* tr = (const float4*)(t_feat + (pb + 16 * s + m) * 16 + q * 8);
                tA[s] = tr[0]; tB[s] = tr[1];
            }
        }
    }

#pragma unroll
    for (int it = 0; it < TPW; ++it) {
        const int pb = max(min(pbase + it * (WAVES * 64), n - 64), 0);

        // keep current x for phase C before the prefetch overwrites it
        const float sx0 = xi0, sx1 = xi1, sx2 = xi2;

        // tanh once per lane on its own point; z-frags pull via bpermute.
        const unsigned pk = pack2bf(fast_tanh(sx1), fast_tanh(sx0));

        // ==== B1: build all 4 z-fragments (consumes tA/tB) ====
        int tp[4];
#pragma unroll
        for (int s = 0; s < 4; ++s)   // lane (q=2,m) needs point 16s+m -> lane 16s+m
            tp[s] = __builtin_amdgcn_ds_bpermute(s * 64 + m4, (int)pk);

        i32x4 zw[4];
#pragma unroll
        for (int s = 0; s < 4; ++s) {
            zw[s][0] = 0; zw[s][1] = 0; zw[s][2] = 0; zw[s][3] = 0;
            if (q < 2) {
                zw[s][0] = (int)pack2bf(tA[s].y, tA[s].x);
                zw[s][1] = (int)pack2bf(tA[s].w, tA[s].z);
                zw[s][2] = (int)pack2bf(tB[s].y, tB[s].x);
                zw[s][3] = (int)pack2bf(tB[s].w, tB[s].z);
            } else if (q == 2) {
                zw[s][0] = tp[s];                  // [tanh(x1)|tanh(x0)]
                zw[s][1] = 0x3F80;                 // k=18: bf16(1.0) bias slot
            }
        }

        // ==== prefetch next iteration's loads (regs just freed) ====
        if (it + 1 < TPW) {
            const int pb2 = max(min(pbase + (it + 1) * (WAVES * 64), n - 64), 0);
            const float* xp = x + (pb2 + lane) * 3;
            xi0 = xp[0]; xi1 = xp[1]; xi2 = xp[2];
            if (q < 2) {
#pragma unroll
                for (int s = 0; s < 4; ++s) {
                    const float4* tr = (const float4*)(t_feat + (pb2 + 16 * s + m) * 16 + q * 8);
                    tA[s] = tr[0]; tB[s] = tr[1];
                }
            }
        }

        // ==== B2: all 16 GEMM1 MFMAs back-to-back (ILP=4 chains) ====
        f32x4 acc[4][4];
#pragma unroll
        for (int s = 0; s < 4; ++s) {
            const bf16x8 zf = __builtin_bit_cast(bf16x8, zw[s]);
#pragma unroll
            for (int a = 0; a < 4; ++a) {
                f32x4 c = { 0.0f, 0.0f, 0.0f, 0.0f };
                acc[s][a] = __builtin_amdgcn_mfma_f32_16x16x32_bf16(w1f[a], zf, c, 0, 0, 0);
            }
        }

        // ==== B3: relu + IN-LANE repack to GEMM2 A-frags (no LDS) ====
        i32x4 a20[4], a21[4];
#pragma unroll
        for (int s = 0; s < 4; ++s) {
            float rl[16];
#pragma unroll
            for (int a = 0; a < 4; ++a)
#pragma unroll
                for (int r = 0; r < 4; ++r)
                    rl[4 * a + r] = fmaxf(acc[s][a][r], 0.0f);
            a20[s][0] = (int)pack2bf(rl[1],  rl[0]);
            a20[s][1] = (int)pack2bf(rl[3],  rl[2]);
            a20[s][2] = (int)pack2bf(rl[5],  rl[4]);
            a20[s][3] = (int)pack2bf(rl[7],  rl[6]);
            a21[s][0] = (int)pack2bf(rl[9],  rl[8]);
            a21[s][1] = (int)pack2bf(rl[11], rl[10]);
            a21[s][2] = (int)pack2bf(rl[13], rl[12]);
            a21[s][3] = (int)pack2bf(rl[15], rl[14]);
        }

        // ==== B4: all 8 GEMM2 MFMAs (2 independent per sub-tile) ====
        f32x4 cd0[4], cd1[4];
        const f32x4 cb = { bias2, bias2, bias2, bias2 };
        const f32x4 cz = { 0.0f, 0.0f, 0.0f, 0.0f };
#pragma unroll
        for (int s = 0; s < 4; ++s) {
            cd0[s] = __builtin_amdgcn_mfma_f32_16x16x32_bf16(
                         __builtin_bit_cast(bf16x8, a20[s]), w2f[0], cb, 0, 0, 0);
            cd1[s] = __builtin_amdgcn_mfma_f32_16x16x32_bf16(
                         __builtin_bit_cast(bf16x8, a21[s]), w2f[1], cz, 0, 0, 0);
        }

        // ==== B5: softplus + d to LDS ====
#pragma unroll
        for (int s = 0; s < 4; ++s)
#pragma unroll
            for (int r = 0; r < 4; ++r) {
                const float dv = fast_softplus(cd0[s][r] + cd1[s][r]) + 0.0001f;
                if (m < 10) lds_d[wave][16 * s + 4 * q + r][m] = dv;
            }

        // ==== phase C: interp + store, all 64 lanes, one point each ====
        {
            const float* dd = lds_d[wave][lane];
            const float dxl2 = dd[0], dxl1 = dd[1], dxr1 = dd[2], dxr2 = dd[3];
            const float dyl2 = dd[4], dyl1 = dd[5], dyr1 = dd[6], dyr2 = dd[7];
            const float kl = dd[8] * 2.0f, kr = dd[9] * 2.0f;

            const float xL1 = -dxl1,        yL1 = -dyl1;
            const float xL2 = -dxl1 - dxl2, yL2 = -dyl1 - dyl2;
            const float xR1 = dxr1,         yR1 = dyr1;
            const float xR2 = dxr1 + dxr2,  yR2 = dyr1 + dyr2;
            const float xR3 = xR2 + BIGC,   yR3 = fmaf(kr, BIGC, yR2);
            const float xL3 = xL2 - BIGC,   yL3 = fmaf(-kl, BIGC, yL2);

            float qx = fminf(fmaxf(sx2, xL3 * 0.99f), xR3 * 0.99f);
            float xl = xL3, xrr = xL2, yl = yL3, yr = yL2;
            if (qx >= xL2) { xl = xL2; xrr = xL1; yl = yL2; yr = yL1; }
            if (qx >= xL1) { xl = xL1; xrr = xR1; yl = yL1; yr = yR1; }
            if (qx >= xR1) { xl = xR1; xrr = xR2; yl = yR1; yr = yR2; }
            if (qx >= xR2) { xl = xR2; xrr = xR3; yl = yR2; yr = yR3; }
            const float slope = (yr - yl) * fast_rcp(xrr - xl);
            const float res = fmaf(slope, qx - xl, yl);

            // pb-clamped => always in-bounds; tail duplicates write identical
            // values from different waves (deterministic) — benign.
            float* op = out + (pb + lane) * 3;
            op[0] = sx0 * m0;
            op[1] = sx1 * m1;
            op[2] = res;
        }
    }
}

extern "C" void kernel_launch(void* const* d_in, const int* in_sizes, int n_in,
                              void* d_out, int out_size, void* d_ws, size_t ws_size,
                              hipStream_t stream) {
    const float* x      = (const float*)d_in[0];
    const float* t_feat = (const float*)d_in[1];
    const float* mask   = (const float*)d_in[2];
    const float* W1     = (const float*)d_in[3];
    const float* b1     = (const float*)d_in[4];
    const float* W2     = (const float*)d_in[5];
    const float* b2     = (const float*)d_in[6];
    float* out = (float*)d_out;

    const int n = in_sizes[0] / 3;                       // 2097152 points
    const int pts_per_block = TPW * WAVES * 64;          // 1024
    const int grid = (n + pts_per_block - 1) / pts_per_block;   // 2048
    coupling_mfma5<<<grid, 256, 0, stream>>>(x, t_feat, mask, W1, b1, W2, b2, out, n);
}